// Round 8
// baseline (686.660 us; speedup 1.0000x reference)
//
#include <hip/hip_runtime.h>
#include <hip/hip_bf16.h>
#include <hip/hip_cooperative_groups.h>
#include <math.h>

namespace cg = cooperative_groups;

#define HW 16384
#define MAXGRID 512

__device__ __forceinline__ float LD(const void* p, long i, int bf){
  return bf ? __bfloat162float(((const __hip_bfloat16*)p)[i]) : ((const float*)p)[i];
}
__device__ __forceinline__ float geluf(float x){ return 0.5f*x*(1.0f + erff(x*0.70710678118654752f)); }
__device__ __forceinline__ int rev7(int i){ return (int)(__brev((unsigned)i)>>25); }

__device__ __forceinline__ void fft128(float* Ar, float* Ai, const float* ct, const float* st,
                                       int lane, float dir){
  #pragma unroll
  for(int len=2; len<=128; len<<=1){
    int half=len>>1;
    int pos = lane & (half-1);
    int i1 = ((lane & ~(half-1))<<1) | pos;
    int i2 = i1 + half;
    int tw = pos * (128/len);
    float wr = ct[tw], wi = dir*st[tw];
    float xr=Ar[i2], xi=Ai[i2];
    float tr = xr*wr - xi*wi;
    float ti = xr*wi + xi*wr;
    float ur=Ar[i1], ui=Ai[i1];
    Ar[i1]=ur+tr; Ai[i1]=ui+ti;
    Ar[i2]=ur-tr; Ai[i2]=ui-ti;
  }
}

#define MAKE_TW(ct,st) { int tt=threadIdx.x; if(tt<128){ float ang=6.283185307179586f*(float)tt/128.f; float s_,c_; sincosf(ang,&s_,&c_); (ct)[tt]=c_; (st)[tt]=s_; } }

// ---- ws layout (float offsets) ----
#define OFF_M    0
#define OFF_G    3072
#define OFF_MB   6144
#define OFF_QDIM 16384
#define OFF_KDIM (16384 + 1048576)
#define OFF_VDIM (16384 + 2*1048576)
#define OFF_QMIX (16384 + 3*1048576)
#define OFF_KMIX (16384 + 4*1048576)
#define OFF_S    (16384 + 5*1048576)
#define FSZ 532480

__global__ __launch_bounds__(256,2)
void k_all(const void* x_in, const void* Wq, const void* Wk, const void* Wv,
           const void* Wr, const void* We, const void* qs_dw, const void* qs_pw,
           const void* qs_g, const void* al_pw, const void* al_dw, const void* ah_pw,
           const void* ah_dw, const void* ph_pw, const void* ph_s, const void* bn_g,
           const void* bn_b, const void* mlp_in, const void* mlp_dw, const void* mlp_out,
           const void* res_s, const void* rescale, const void* Wproj, const void* bproj,
           float* ws, void* out){
  cg::grid_group grid = cg::this_grid();
  __shared__ float smem[15936];     // 63744 B union across phases
  int t = threadIdx.x;
  int NG = (int)gridDim.x;
  int bf; { float v0 = ((const float*)bn_g)[0]; bf = (v0==1.0f) ? 0 : 1; }

  float* FA = ws + OFF_S;
  float* FB = FA + FSZ;
  float* FC = FB + FSZ;
  float* FD = FC + FSZ;
  float* FE = FD + FSZ;
  float* M96 = FE + FSZ;
  float* G96 = ws + OFF_QDIM;       // overlays qd/kd after they die
  float* qd = ws + OFF_QDIM;
  float* kd = ws + OFF_KDIM;
  float* vd = ws + OFF_VDIM;
  float* qm = ws + OFF_QMIX;
  float* km = ws + OFF_KMIX;

  // ---------------- P0: fold M (48) + zero accumulators (task 48) ----------------
  for(int task=blockIdx.x; task<49; task+=NG){
    if(task==48){
      for(int i=3072+t;i<10240;i+=256) ws[i]=0.f;
    } else {
      float* wr = smem;            // 8192
      float* part = smem+8192;     // 256
      int mat=task>>4, seg=task&15;
      const void* Wsrc = mat==0 ? Wq : (mat==1 ? Wk : Wv);
      for(int i=t;i<8192;i+=256) wr[i]=LD(Wr,i,bf);
      __syncthreads();
      int o=t&63, jseg=t>>6;
      int c=seg*4+(o>>4), r=o&15;
      float acc=0.f;
      for(int j=jseg*128;j<jseg*128+128;j++) acc += LD(Wsrc,(long)c*512+j,bf)*wr[j*16+r];
      part[jseg*64+o]=acc;
      __syncthreads();
      if(t<64){
        float s=part[t]+part[64+t]+part[128+t]+part[192+t];
        int cc=seg*4+(t>>4), rr=t&15;
        ws[mat*1024 + cc*16 + rr]=s;
      }
      __syncthreads();
    }
  }
  grid.sync();

  // ---------------- P1: dims (4096 tasks) ----------------
  {
    float* xs = smem;          // 1024
    float* ms = smem+1024;     // 3072
    for(int i=t;i<3072;i+=256) ms[i]=ws[i];
    __syncthreads();
    for(int task=blockIdx.x; task<4096; task+=NG){
      int b = task>>10;
      int pix0 = (task & 1023)<<4;
      long base = ((long)b*HW + pix0)*64;
      for(int i=t;i<1024;i+=256) xs[i]=LD(x_in, base+i, bf);
      __syncthreads();
      int p=t>>4, r=t&15;
      float aq=0.f,ak=0.f,av=0.f;
      for(int c=0;c<64;c++){
        float xv = xs[p*64+c];
        aq += xv*ms[c*16+r];
        ak += xv*ms[1024+c*16+r];
        av += xv*ms[2048+c*16+r];
      }
      long o = ((long)b*HW + pix0)*16 + t;
      qd[o]=aq; kd[o]=ak; vd[o]=av;
      __syncthreads();
    }
  }
  grid.sync();

  // ---------------- P2: spatial(256) | fft_row(256) | wave_a(1024) ----------------
  for(int task=blockIdx.x; task<1536; task+=NG){
    if(task<256){
      float* tile=smem; float* dws=smem+8704; float* pws=smem+8848; float* gsm=smem+9104;
      int b=task>>6, y0=(task&63)<<1;
      for(int i=t;i<144;i+=256) dws[i]=LD(qs_dw,i,bf);
      if(t<256) pws[t]=LD(qs_pw,t,bf);
      if(t<16) gsm[t]=LD(qs_g,t,bf);
      __syncthreads();
      for(int i=t;i<8192;i+=256){
        int ry=i>>11, rem=i&2047, xx=rem>>4, ch=rem&15;
        int yy=y0-1+ry;
        tile[(ry*128+xx)*17+ch] = (yy>=0&&yy<128) ? qd[(long)(b*128+yy)*2048 + rem] : 0.f;
      }
      __syncthreads();
      int ty=t>>7, x=t&127;
      float g[16];
      for(int ch=0;ch<16;ch++){
        float acc=0.f;
        for(int p=0;p<3;p++)
          for(int q=0;q<3;q++){
            int xx=x-1+q;
            if(xx>=0&&xx<128) acc += dws[ch*9+p*3+q]*tile[((ty+p)*128+xx)*17+ch];
          }
        g[ch]=geluf(acc);
      }
      long ob = ((long)(b*128+y0+ty)*128 + x)*16;
      for(int c=0;c<16;c++){
        float acc=0.f;
        for(int ch=0;ch<16;ch++) acc += pws[c*16+ch]*g[ch];
        qm[ob+c] = tile[((1+ty)*128+x)*17+c] + gsm[c]*acc;
      }
      __syncthreads();
    } else if(task<512){
      float* slab=smem; float* outre=smem+4160; float* outim=smem+6272;
      float* Ar=smem+8384; float* Ai=smem+8896; float* ct=smem+9408; float* st=smem+9536;
      int blk2=task-256;
      int b=blk2>>6, y0=(blk2&63)<<1;
      MAKE_TW(ct,st);
      long gbase = ((long)(b*128+y0))*2048;
      for(int e=t;e<4096;e+=256){
        int yl=e>>11, rem=e&2047, x=rem>>4, c=rem&15;
        slab[yl*2080 + c*130 + x] = kd[gbase + e];
      }
      __syncthreads();
      int w=t>>6, l=t&63, wb=w<<7;
      for(int li=w; li<32; li+=4){
        int yl=li>>4, c=li&15;
        int sb = yl*2080 + c*130;
        float v0=slab[sb+l], v1=slab[sb+64+l];
        int r0=rev7(l), r1=rev7(64+l);
        Ar[wb+r0]=v0; Ai[wb+r0]=0.f;
        Ar[wb+r1]=v1; Ai[wb+r1]=0.f;
        fft128(Ar+wb, Ai+wb, ct, st, l, -1.f);
        int ob = yl*1056 + c*66;
        outre[ob+l]=Ar[wb+l]; outim[ob+l]=Ai[wb+l];
        if(l==0){ outre[ob+64]=Ar[wb+64]; outim[ob+64]=Ai[wb+64]; }
      }
      __syncthreads();
      long obase = ((long)(b*128+y0))*1040;
      for(int e=t;e<2080;e+=256){
        int yl=e/1040, rem=e%1040, v=rem>>4, c=rem&15;
        FA[obase+e]=outre[yl*1056 + c*66 + v];
        FB[obase+e]=outim[yl*1056 + c*66 + v];
      }
      __syncthreads();
    } else {
      float* wi=smem; float* vds=smem+4608; float* ns=smem+5632;
      float* gsm=smem+6400; float* bsm=smem+6448;
      int blk3=task-512;
      int b = blk3>>8;
      int ij0 = (blk3&255)<<4;
      for(int i=t;i<4608;i+=256){ int cc=i/96, ch=i%96; wi[cc*96+ch]=LD(mlp_in,(long)ch*48+cc,bf); }
      if(t<48){ gsm[t]=LD(bn_g,t,bf)*(1.f/sqrtf(1.f+1e-5f)); bsm[t]=LD(bn_b,t,bf); }
      int i0 = ij0>>6, j0 = ij0&63;
      long rb0 = ((long)(b*128 + 2*i0)*128 + 2*j0)*16;
      for(int i=t;i<512;i+=256){ vds[i]=vd[rb0+i]; vds[512+i]=vd[rb0+2048+i]; }
      __syncthreads();
      for(int o=t;o<768;o+=256){
        int p=o/48, cc2=o%48;
        int m=cc2+16, c=m>>2, f=m&3;
        float a =vds[(2*p)*16+c],     bv=vds[(2*p+1)*16+c];
        float cv=vds[512+(2*p)*16+c], dv=vds[512+(2*p+1)*16+c];
        float v;
        if(f==0)      v=(a+bv+cv+dv);
        else if(f==1) v=(a-bv+cv-dv);
        else if(f==2) v=(a+bv-cv-dv);
        else          v=(a-bv-cv+dv);
        ns[o] = v*0.5f*gsm[cc2]+bsm[cc2];
      }
      __syncthreads();
      long ob = ((long)b*4096 + ij0)*96;
      for(int o=t;o<1536;o+=256){
        int p=o/96, ch=o%96;
        float acc=0.f;
        for(int cc=0;cc<48;cc++) acc += wi[cc*96+ch]*ns[p*48+cc];
        M96[ob+o]=acc;
      }
      __syncthreads();
    }
  }
  grid.sync();

  // ---------------- P3: fft_col + mix (260 tasks) ----------------
  for(int task=blockIdx.x; task<260; task+=NG){
    float* sre=smem;        float* sim=smem+2080;
    float* og=smem+4160;    float* oh=smem+6240;   float* op=smem+8320;
    float* Ar=smem+10400;   float* Ai=smem+10912;
    float* ct=smem+11424;   float* st=smem+11552;
    float* wl=smem+11680;   float* wh=smem+11936;  float* wp=smem+12192;
    int b = task/65, v = task%65;
    MAKE_TW(ct,st);
    wl[t]=LD(al_pw,t,bf); wh[t]=LD(ah_pw,t,bf); wp[t]=LD(ph_pw,t,bf);
    long ibase = ((long)b*128)*1040 + v*16;
    for(int e=t;e<2048;e+=256){
      int y=e>>4, c=e&15;
      sre[c*130+y]=FA[ibase + (long)y*1040 + c];
      sim[c*130+y]=FB[ibase + (long)y*1040 + c];
    }
    __syncthreads();
    int w=t>>6, l=t&63, wb=w<<7;
    const float inv=1.f/128.f;
    for(int c=w; c<16; c+=4){
      int sb=c*130;
      float x0r=sre[sb+l], x0i=sim[sb+l], x1r=sre[sb+64+l], x1i=sim[sb+64+l];
      int r0=rev7(l), r1=rev7(64+l);
      Ar[wb+r0]=x0r; Ai[wb+r0]=x0i;
      Ar[wb+r1]=x1r; Ai[wb+r1]=x1i;
      fft128(Ar+wb, Ai+wb, ct, st, l, -1.f);
      float re0=Ar[wb+l]*inv, im0=Ai[wb+l]*inv;
      float re1=Ar[wb+64+l]*inv, im1=Ai[wb+64+l]*inv;
      sre[sb+l]=sqrtf(re0*re0+im0*im0); sim[sb+l]=atan2f(im0,re0);
      sre[sb+64+l]=sqrtf(re1*re1+im1*im1); sim[sb+64+l]=atan2f(im1,re1);
    }
    __syncthreads();
    {
      int u = t&127, half = t>>7;
      float yy=(float)u/127.f, xx=(float)v/64.f;
      float rr=sqrtf(yy*yy+xx*xx);
      float lo = 1.f/(1.f+expf((rr-0.25f)*20.f));
      float hi = 1.f-lo;
      float av[16], pv[16];
      for(int ch=0;ch<16;ch++){ av[ch]=sre[ch*130+u]; pv[ch]=sim[ch*130+u]; }
      float pscale = LD(ph_s,0,bf);
      for(int c=half*8;c<half*8+8;c++){
        float al=0.f, ah=0.f, pp=0.f;
        for(int ch=0;ch<16;ch++){
          float a=av[ch];
          al += wl[c*16+ch]*(a*lo);
          ah += wh[c*16+ch]*(a*hi);
          pp += wp[c*16+ch]*pv[ch];
        }
        og[c*130+u]=geluf(al); oh[c*130+u]=geluf(ah); op[c*130+u]=pv[c]+pscale*pp;
      }
    }
    __syncthreads();
    for(int e=t;e<2048;e+=256){
      int u=e>>4, c=e&15;
      long o = ibase + (long)u*1040 + c;
      FC[o]=og[c*130+u]; FD[o]=oh[c*130+u]; FE[o]=op[c*130+u];
    }
    __syncthreads();
  }
  grid.sync();

  // ---------------- P4: four_dw (2080 tasks) ----------------
  {
    float* wl=smem; float* wh=smem+144;
    if(t<144){ wl[t]=LD(al_dw,t,bf); wh[t]=LD(ah_dw,t,bf); }
    __syncthreads();
    for(int task=blockIdx.x; task<2080; task+=NG){
      long o = (long)task*256+t;
      int c=(int)(o&15); long r=o>>4; int v=(int)(r%65); long r2=r/65; int u=(int)(r2&127); int b=(int)(r2>>7);
      float acc=0.f;
      for(int dp=0;dp<3;dp++){
        int uu=u-1+dp; if(uu<0||uu>=128) continue;
        for(int dq=0;dq<3;dq++){
          int vv=v-1+dq; if(vv<0||vv>=65) continue;
          long idx=(((long)(b*128+uu))*65+vv)*16+c;
          acc += wl[c*9+dp*3+dq]*FC[idx] + wh[c*9+dp*3+dq]*FD[idx];
        }
      }
      float pvv = FE[o];
      float s_,c_; sincosf(pvv,&s_,&c_);
      FA[o]=acc*c_; FB[o]=acc*s_;
    }
  }
  grid.sync();

  // ---------------- P5: ifft_col (260 tasks) ----------------
  for(int task=blockIdx.x; task<260; task+=NG){
    float* sre=smem; float* sim=smem+2080;
    float* Ar=smem+4160; float* Ai=smem+4672;
    float* ct=smem+5184; float* st=smem+5312;
    int b = task/65, v = task%65;
    MAKE_TW(ct,st);
    long ibase = ((long)b*128)*1040 + v*16;
    for(int e=t;e<2048;e+=256){
      int u=e>>4, c=e&15;
      sre[c*130+u]=FA[ibase + (long)u*1040 + c];
      sim[c*130+u]=FB[ibase + (long)u*1040 + c];
    }
    __syncthreads();
    int w=t>>6, l=t&63, wb=w<<7;
    for(int c=w; c<16; c+=4){
      int sb=c*130;
      float x0r=sre[sb+l], x0i=sim[sb+l], x1r=sre[sb+64+l], x1i=sim[sb+64+l];
      int r0=rev7(l), r1=rev7(64+l);
      Ar[wb+r0]=x0r; Ai[wb+r0]=x0i;
      Ar[wb+r1]=x1r; Ai[wb+r1]=x1i;
      fft128(Ar+wb, Ai+wb, ct, st, l, +1.f);
      sre[sb+l]=Ar[wb+l]; sim[sb+l]=Ai[wb+l];
      sre[sb+64+l]=Ar[wb+64+l]; sim[sb+64+l]=Ai[wb+64+l];
    }
    __syncthreads();
    for(int e=t;e<2048;e+=256){
      int y=e>>4, c=e&15;
      FC[ibase + (long)y*1040 + c]=sre[c*130+y];
      FD[ibase + (long)y*1040 + c]=sim[c*130+y];
    }
    __syncthreads();
  }
  grid.sync();

  // ---------------- P6: ifft_row(256) | wave_dw(6144) ----------------
  {
    float* wdw = smem+12000;   // outside ifft_row's [0,9664)
    for(int i=t;i<864;i+=256) wdw[i]=LD(mlp_dw,i,bf);
    __syncthreads();
    for(int task=blockIdx.x; task<6400; task+=NG){
      if(task<256){
        float* szre=smem; float* szim=smem+2112; float* oslab=smem+4224;
        float* Ar=smem+8384; float* Ai=smem+8896; float* ct=smem+9408; float* st=smem+9536;
        int b = task>>6, y0 = (task&63)<<1;
        MAKE_TW(ct,st);
        long ibase = ((long)(b*128+y0))*1040;
        for(int e=t;e<2080;e+=256){
          int yl=e/1040, rem=e%1040, v=rem>>4, c=rem&15;
          szre[yl*1056 + c*66 + v]=FC[ibase+e];
          szim[yl*1056 + c*66 + v]=FD[ibase+e];
        }
        __syncthreads();
        int w=t>>6, l=t&63, wb=w<<7;
        const float inv=1.f/128.f;
        for(int li=w; li<32; li+=4){
          int yl=li>>4, c=li&15;
          int sb = yl*1056 + c*66;
          float zr0 = szre[sb+l];
          float zi0 = (l==0)?0.f:szim[sb+l];
          float zr1, zi1;
          if(l==0){ zr1=szre[sb+64]; zi1=0.f; }
          else    { zr1=szre[sb+64-l]; zi1=-szim[sb+64-l]; }
          int r0=rev7(l), r1=rev7(64+l);
          Ar[wb+r0]=zr0; Ai[wb+r0]=zi0;
          Ar[wb+r1]=zr1; Ai[wb+r1]=zi1;
          fft128(Ar+wb, Ai+wb, ct, st, l, +1.f);
          int ob = yl*2080 + c*130;
          oslab[ob+l]=Ar[wb+l]*inv;
          oslab[ob+64+l]=Ar[wb+64+l]*inv;
        }
        __syncthreads();
        long obase = ((long)(b*128+y0))*2048;
        for(int e=t;e<4096;e+=256){
          int yl=e>>11, rem=e&2047, x=rem>>4, c=rem&15;
          km[obase+e]=oslab[yl*2080 + c*130 + x];
        }
        __syncthreads();
      } else {
        int o = (task-256)*256+t;   // 1,572,864 exact
        int ch = o%96; int r = o/96; int px = r&4095; int b = r>>12;
        int i = px>>6, j = px&63;
        long mb = (long)b*393216;
        float acc=0.f;
        for(int dp=0;dp<3;dp++){ int ii=i-1+dp; if(ii<0||ii>=64) continue;
          for(int dq=0;dq<3;dq++){ int jj=j-1+dq; if(jj<0||jj>=64) continue;
            acc += wdw[ch*9+dp*3+dq]*M96[mb + (long)(ii*64+jj)*96 + ch]; } }
        G96[o]=geluf(acc);
      }
    }
  }
  grid.sync();

  // ---------------- P7: gram (128 tasks) ----------------
  for(int task=blockIdx.x; task<128; task+=NG){
    float* qs=smem; float* ks=smem+4096;
    int b=task>>5; int chunk=task&31;
    int r=t>>4, s=t&15;
    float akq=0.f, akk=0.f, aqq=0.f;
    for(int tile=0;tile<2;tile++){
      long pb=((long)b*HW + chunk*512 + tile*256)*16;
      for(int i=t;i<4096;i+=256){ qs[i]=qm[pb+i]; ks[i]=km[pb+i]; }
      __syncthreads();
      for(int p=0;p<256;p++){
        float kv=ks[p*16+r], qv=qs[p*16+s];
        akq += kv*qv;
        akk += kv*ks[p*16+s];
        aqq += qs[p*16+r]*qv;
      }
      __syncthreads();
    }
    float* Gb=ws + OFF_G + b*768;
    atomicAdd(&Gb[t], akq);
    atomicAdd(&Gb[256+t], akk);
    atomicAdd(&Gb[512+t], aqq);
  }
  grid.sync();

  // ---------------- P8: attn (32 tasks) ----------------
  for(int task=blockIdx.x; task<32; task+=NG){
    float* wes=smem;            // 1024
    float* gkq=smem+1024; float* gkk=smem+1280; float* gqq=smem+1536;
    float* ukq=smem+1792; float* ukk=smem+2816; float* uqq=smem+3840;
    float* nk=smem+4864;  float* nq=smem+4928;
    float* A=smem+4992;         // 4096
    float* T=smem+9088;         // 1024
    int b=task>>3, h=task&7;
    const float* G=ws+OFF_G;
    for(int i=t;i<1024;i+=256){ int rr=i>>6, e=i&63; wes[rr*64+e]=LD(We, (long)rr*512 + h*64 + e, bf); }
    gkq[t]=G[b*768+t]; gkk[t]=G[b*768+256+t]; gqq[t]=G[b*768+512+t];
    __syncthreads();
    for(int i=t;i<1024;i+=256){
      int d=i>>4, s=i&15;
      float a1=0.f,a2=0.f,a3=0.f;
      for(int rr=0;rr<16;rr++){ float wv=wes[rr*64+d]; a1+=wv*gkq[rr*16+s]; a2+=wv*gkk[rr*16+s]; a3+=wv*gqq[rr*16+s]; }
      ukq[i]=a1; ukk[i]=a2; uqq[i]=a3;
    }
    __syncthreads();
    if(t<64){ float a=0.f; for(int s=0;s<16;s++) a+=ukk[t*16+s]*wes[s*64+t]; nk[t]=fmaxf(sqrtf(a),1e-12f); }
    else if(t<128){ int e=t-64; float a=0.f; for(int s=0;s<16;s++) a+=uqq[e*16+s]*wes[s*64+e]; nq[e]=fmaxf(sqrtf(a),1e-12f); }
    __syncthreads();
    float rsc=LD(rescale,h,bf);
    for(int i=t;i<4096;i+=256){
      int d=i>>6, e=i&63;
      float a=0.f; for(int s=0;s<16;s++) a+=ukq[d*16+s]*wes[s*64+e];
      A[i]=a/(nk[d]*nq[e])*rsc;
    }
    __syncthreads();
    if(t<64){
      int d=t; float m=-1e30f;
      for(int e=0;e<64;e++) m=fmaxf(m,A[d*64+e]);
      float sum=0.f;
      for(int e=0;e<64;e++){ float ev=expf(A[d*64+e]-m); A[d*64+e]=ev; sum+=ev; }
      float inv=1.f/sum;
      for(int e=0;e<64;e++) A[d*64+e]*=inv;
    }
    __syncthreads();
    for(int i=t;i<1024;i+=256){
      int d=i>>4, s=i&15;
      float a=0.f; for(int e=0;e<64;e++) a+=A[d*64+e]*wes[s*64+e];
      T[i]=a;
    }
    __syncthreads();
    for(int i=t;i<1024;i+=256){
      int s=i>>6, c=i&63;
      float a=0.f;
      for(int d=0;d<64;d++) a+=T[d*16+s]*LD(Wproj,(long)(h*64+d)*64+c,bf);
      atomicAdd(&ws[OFF_MB + b*1024 + s*64 + c], a);
    }
    __syncthreads();
  }
  grid.sync();

  // ---------------- P9: epi (256 tasks) ----------------
  for(int task=blockIdx.x; task<256; task+=NG){
    float* wt=smem;          // 4608
    float* gt=smem+4608;     // 6144
    float* he=smem+10752;    // 4096
    float* mb=smem+14848;    // 1024
    float* bias=smem+15872;  // 64
    int b=task>>6; int tile=task&63;
    int i0=(tile>>3)<<3, j0=(tile&7)<<3;
    for(int i=t;i<4608;i+=256){ int ch=i/48, cc=i%48; wt[ch*48+cc]=LD(mlp_out,(long)cc*96+ch,bf); }
    for(int i=t;i<6144;i+=256){
      int px=i/96, ch=i%96;
      int gi=i0+(px>>3), gj=j0+(px&7);
      gt[i]=G96[((long)b*4096 + gi*64+gj)*96 + ch];
    }
    for(int i=t;i<1024;i+=256) mb[i]=ws[OFF_MB + b*1024 + i];
    if(t<64) bias[t]=LD(bproj,t,bf);
    __syncthreads();
    float rs=LD(res_s,0,bf);
    for(int o=t;o<3072;o+=256){
      int px=o/48, cc=o%48;
      int gi=i0+(px>>3), gj=j0+(px&7);
      float acc=0.f;
      for(int ch=0;ch<96;ch++) acc += wt[ch*48+cc]*gt[px*96+ch];
      long vb = ((long)(b*128+2*gi)*128 + 2*gj)*16;
      int m=cc+16, c=m>>2, f=m&3;
      float a=vd[vb+c], bv=vd[vb+16+c], cv=vd[vb+2048+c], dv=vd[vb+2048+16+c];
      float hv;
      if(f==0)      hv=(a+bv+cv+dv);
      else if(f==1) hv=(a-bv+cv-dv);
      else if(f==2) hv=(a+bv-cv-dv);
      else          hv=(a-bv-cv+dv);
      he[px*64 + 16 + cc] = hv*0.5f + rs*acc;
    }
    for(int o=t;o<1024;o+=256){
      int px=o>>4, c16=o&15;
      int gi=i0+(px>>3), gj=j0+(px&7);
      long vb=((long)(b*128+2*gi)*128+2*gj)*16;
      int c=c16>>2, f=c16&3;
      float a=vd[vb+c], bv=vd[vb+16+c], cv=vd[vb+2048+c], dv=vd[vb+2048+16+c];
      float hv;
      if(f==0)      hv=(a+bv+cv+dv);
      else if(f==1) hv=(a-bv+cv-dv);
      else if(f==2) hv=(a+bv-cv-dv);
      else          hv=(a-bv-cv+dv);
      he[px*64+c16]=hv*0.5f;
    }
    __syncthreads();
    for(int ok=t; ok<16384; ok+=256){
      int c=ok&63, px=ok>>6;
      int orow=px>>4, ocol=px&15;
      int halfpx=(orow>>1)*8 + (ocol>>1);
      int pos=((orow&1)<<1)|(ocol&1);
      const float* hv = he + halfpx*64 + pos*16;
      float acc=bias[c];
      for(int s=0;s<16;s++) acc += hv[s]*mb[s*64+c];
      long oo = (((long)(b*128 + 2*i0+orow))*128 + (2*j0+ocol))*64 + c;
      if(bf) ((__hip_bfloat16*)out)[oo]=__float2bfloat16(acc);
      else   ((float*)out)[oo]=acc;
    }
    __syncthreads();
  }
}

extern "C" void kernel_launch(void* const* d_in, const int* in_sizes, int n_in,
                              void* d_out, int out_size, void* d_ws, size_t ws_size,
                              hipStream_t stream) {
  void* x_in   = d_in[0];
  void* Wq     = d_in[1];
  void* Wk     = d_in[2];
  void* Wv     = d_in[3];
  void* Wr     = d_in[4];
  void* We     = d_in[5];
  void* qs_dw  = d_in[6];
  void* qs_pw  = d_in[7];
  void* qs_g   = d_in[8];
  void* al_pw  = d_in[9];
  void* al_dw  = d_in[10];
  void* ah_pw  = d_in[11];
  void* ah_dw  = d_in[12];
  void* ph_pw  = d_in[13];
  void* ph_s   = d_in[14];
  void* bn_g   = d_in[15];
  void* bn_b   = d_in[16];
  void* mlp_in = d_in[17];
  void* mlp_dw = d_in[18];
  void* mlp_out= d_in[19];
  void* res_s  = d_in[20];
  void* rescale= d_in[21];
  void* Wproj  = d_in[22];
  void* bproj  = d_in[23];
  float* ws = (float*)d_ws;
  void* outp = d_out;

  // Runtime-derived cooperative grid: guaranteed co-resident.
  int blocksPerCU = 0;
  hipError_t oe = hipOccupancyMaxActiveBlocksPerMultiprocessor(
      &blocksPerCU, (const void*)k_all, 256, 0);
  if(oe != hipSuccess || blocksPerCU < 1) blocksPerCU = 1;
  int grid = blocksPerCU * 256;
  if(grid > MAXGRID) grid = MAXGRID;

  void* params[] = {
    &x_in, &Wq, &Wk, &Wv, &Wr, &We, &qs_dw, &qs_pw, &qs_g,
    &al_pw, &al_dw, &ah_pw, &ah_dw, &ph_pw, &ph_s, &bn_g, &bn_b,
    &mlp_in, &mlp_dw, &mlp_out, &res_s, &rescale, &Wproj, &bproj,
    &ws, &outp
  };
  hipLaunchCooperativeKernel((const void*)k_all, dim3(grid), dim3(256),
                             params, 0, stream);
}

// Round 9
// 587.019 us; speedup vs baseline: 1.1697x; 1.1697x over previous
//
#include <hip/hip_runtime.h>
#include <hip/hip_bf16.h>
#include <math.h>

#define HW 16384

__device__ __forceinline__ float LD(const void* p, long i, int bf){
  return bf ? __bfloat162float(((const __hip_bfloat16*)p)[i]) : ((const float*)p)[i];
}
__device__ __forceinline__ float geluf(float x){ return 0.5f*x*(1.0f + erff(x*0.70710678118654752f)); }
__device__ __forceinline__ int rev7(int i){ return (int)(__brev((unsigned)i)>>25); }

__device__ __forceinline__ void fft128(float* Ar, float* Ai, const float* ct, const float* st,
                                       int lane, float dir){
  #pragma unroll
  for(int len=2; len<=128; len<<=1){
    int half=len>>1;
    int pos = lane & (half-1);
    int i1 = ((lane & ~(half-1))<<1) | pos;
    int i2 = i1 + half;
    int tw = pos * (128/len);
    float wr = ct[tw], wi = dir*st[tw];
    float xr=Ar[i2], xi=Ai[i2];
    float tr = xr*wr - xi*wi;
    float ti = xr*wi + xi*wr;
    float ur=Ar[i1], ui=Ai[i1];
    Ar[i1]=ur+tr; Ai[i1]=ui+ti;
    Ar[i2]=ur-tr; Ai[i2]=ui-ti;
  }
}

#define MAKE_TWP(ct,st) { int tt=threadIdx.x; if(tt<128){ float ang=6.283185307179586f*(float)tt/128.f; float s_,c_; sincosf(ang,&s_,&c_); (ct)[tt]=c_; (st)[tt]=s_; } }

// ---- ws layout (float offsets) ----
#define OFF_M    0
#define OFF_G    3072
#define OFF_MB   6144
#define OFF_FLAG 10240
#define OFF_QDIM 16384
#define OFF_KDIM (16384 + 1048576)
#define OFF_VDIM (16384 + 2*1048576)
#define OFF_QMIX (16384 + 3*1048576)
#define OFF_KMIX (16384 + 4*1048576)
#define OFF_S    (16384 + 5*1048576)
#define FSZ 532480

// K0: fold (48 blocks) + flag/zero (block 48)
__global__ void k_head(const void* Wq, const void* Wk, const void* Wv,
                       const void* Wr, const void* bng, float* ws){
  __shared__ float wr[8192];
  __shared__ float part[256];
  int blk=blockIdx.x, t=threadIdx.x;
  if(blk==48){
    for(int i=3072+t;i<10240;i+=256) ws[i]=0.f;
    if(t==0){
      float v = ((const float*)bng)[0];
      ((int*)ws)[OFF_FLAG] = (v==1.0f) ? 0 : 1;
    }
    return;
  }
  int bf = (((const float*)bng)[0]==1.0f) ? 0 : 1;
  int mat=blk>>4, seg=blk&15;
  const void* Wsrc = mat==0 ? Wq : (mat==1 ? Wk : Wv);
  for(int i=t;i<8192;i+=256) wr[i]=LD(Wr,i,bf);
  __syncthreads();
  int o=t&63, jseg=t>>6;
  int c=seg*4+(o>>4), r=o&15;
  float acc=0.f;
  for(int j=jseg*128;j<jseg*128+128;j++) acc += LD(Wsrc,(long)c*512+j,bf)*wr[j*16+r];
  part[jseg*64+o]=acc;
  __syncthreads();
  if(t<64){
    float s=part[t]+part[64+t]+part[128+t]+part[192+t];
    int cc=seg*4+(t>>4), rr=t&15;
    ws[mat*1024 + cc*16 + rr]=s;
  }
}

// K1: q/k/v_dim = x @ M{q,k,v}
__global__ void k_dims(const void* x, const float* ws,
                       float* qd, float* kd, float* vd, const int* flg){
  int bf=*flg;
  __shared__ float xs[16*64];
  __shared__ float ms[3*1024];
  int b = blockIdx.x>>10;
  int pix0 = (blockIdx.x & 1023)<<4;
  int t = threadIdx.x;
  for(int i=t;i<3072;i+=256) ms[i]=ws[i];
  long base = ((long)b*HW + pix0)*64;
  for(int i=t;i<1024;i+=256) xs[i]=LD(x, base+i, bf);
  __syncthreads();
  int p=t>>4, r=t&15;
  float aq=0.f,ak=0.f,av=0.f;
  for(int c=0;c<64;c++){
    float xv = xs[p*64+c];
    aq += xv*ms[c*16+r];
    ak += xv*ms[1024+c*16+r];
    av += xv*ms[2048+c*16+r];
  }
  long o = ((long)b*HW + pix0)*16 + t;
  qd[o]=aq; kd[o]=ak; vd[o]=av;
}

// K2 merged: [0,256) spatial (2 rows/blk) | [256,512) fft_row | [512,1536) wave_a
__global__ void k_mix3(const float* qd, float* qm, const void* dw, const void* pw, const void* gamma,
                       const float* kd, float* Rre, float* Rim,
                       const float* vd, float* m96, const void* win, const void* bng, const void* bnb,
                       const int* flg){
  __shared__ float smem[9664];
  int bf=*flg;
  int blk=blockIdx.x, t=threadIdx.x;
  if(blk<256){
    float* tile=smem; float* dws=smem+8704; float* pws=smem+8848; float* gsm=smem+9104;
    int b=blk>>6, y0=(blk&63)<<1;
    for(int i=t;i<144;i+=256) dws[i]=LD(dw,i,bf);
    if(t<256) pws[t]=LD(pw,t,bf);
    if(t<16) gsm[t]=LD(gamma,t,bf);
    for(int i=t;i<8192;i+=256){
      int ry=i>>11, rem=i&2047, xx=rem>>4, ch=rem&15;
      int yy=y0-1+ry;
      tile[(ry*128+xx)*17+ch] = (yy>=0&&yy<128) ? qd[(long)(b*128+yy)*2048 + rem] : 0.f;
    }
    __syncthreads();
    int ty=t>>7, x=t&127;
    float g[16];
    for(int ch=0;ch<16;ch++){
      float acc=0.f;
      for(int p=0;p<3;p++)
        for(int q=0;q<3;q++){
          int xx=x-1+q;
          if(xx>=0&&xx<128) acc += dws[ch*9+p*3+q]*tile[((ty+p)*128+xx)*17+ch];
        }
      g[ch]=geluf(acc);
    }
    long ob = ((long)(b*128+y0+ty)*128 + x)*16;
    for(int c=0;c<16;c++){
      float acc=0.f;
      for(int ch=0;ch<16;ch++) acc += pws[c*16+ch]*g[ch];
      qm[ob+c] = tile[((1+ty)*128+x)*17+c] + gsm[c]*acc;
    }
  } else if(blk<512){
    float* slab=smem; float* outre=smem+4160; float* outim=smem+6272;
    float* Ar=smem+8384; float* Ai=smem+8896; float* ct=smem+9408; float* st=smem+9536;
    int blk2=blk-256;
    int b=blk2>>6, y0=(blk2&63)<<1;
    MAKE_TWP(ct,st);
    long gbase = ((long)(b*128+y0))*2048;
    for(int e=t;e<4096;e+=256){
      int yl=e>>11, rem=e&2047, x=rem>>4, c=rem&15;
      slab[yl*2080 + c*130 + x] = kd[gbase + e];
    }
    __syncthreads();
    int w=t>>6, l=t&63, wb=w<<7;
    for(int li=w; li<32; li+=4){
      int yl=li>>4, c=li&15;
      int sb = yl*2080 + c*130;
      float v0=slab[sb+l], v1=slab[sb+64+l];
      int r0=rev7(l), r1=rev7(64+l);
      Ar[wb+r0]=v0; Ai[wb+r0]=0.f;
      Ar[wb+r1]=v1; Ai[wb+r1]=0.f;
      fft128(Ar+wb, Ai+wb, ct, st, l, -1.f);
      int ob = yl*1056 + c*66;
      outre[ob+l]=Ar[wb+l]; outim[ob+l]=Ai[wb+l];
      if(l==0){ outre[ob+64]=Ar[wb+64]; outim[ob+64]=Ai[wb+64]; }
    }
    __syncthreads();
    long obase = ((long)(b*128+y0))*1040;
    for(int e=t;e<2080;e+=256){
      int yl=e/1040, rem=e%1040, v=rem>>4, c=rem&15;
      Rre[obase+e]=outre[yl*1056 + c*66 + v];
      Rim[obase+e]=outim[yl*1056 + c*66 + v];
    }
  } else {
    float* wi=smem; float* vds=smem+4608; float* ns=smem+5632;
    float* gsm=smem+6400; float* bsm=smem+6448;
    int blk3=blk-512;
    int b = blk3>>8;
    int ij0 = (blk3&255)<<4;
    for(int i=t;i<4608;i+=256){ int cc=i/96, ch=i%96; wi[cc*96+ch]=LD(win,(long)ch*48+cc,bf); }
    if(t<48){ gsm[t]=LD(bng,t,bf)*(1.f/sqrtf(1.f+1e-5f)); bsm[t]=LD(bnb,t,bf); }
    int i0 = ij0>>6, j0 = ij0&63;
    long rb0 = ((long)(b*128 + 2*i0)*128 + 2*j0)*16;
    for(int i=t;i<512;i+=256){ vds[i]=vd[rb0+i]; vds[512+i]=vd[rb0+2048+i]; }
    __syncthreads();
    for(int o=t;o<768;o+=256){
      int p=o/48, cc2=o%48;
      int m=cc2+16, c=m>>2, f=m&3;
      float a =vds[(2*p)*16+c],     bv=vds[(2*p+1)*16+c];
      float cv=vds[512+(2*p)*16+c], dv=vds[512+(2*p+1)*16+c];
      float v;
      if(f==0)      v=(a+bv+cv+dv);
      else if(f==1) v=(a-bv+cv-dv);
      else if(f==2) v=(a+bv-cv-dv);
      else          v=(a-bv-cv+dv);
      ns[o] = v*0.5f*gsm[cc2]+bsm[cc2];
    }
    __syncthreads();
    long ob = ((long)b*4096 + ij0)*96;
    for(int o=t;o<1536;o+=256){
      int p=o/96, ch=o%96;
      float acc=0.f;
      for(int cc=0;cc<48;cc++) acc += wi[cc*96+ch]*ns[p*48+cc];
      m96[ob+o]=acc;
    }
  }
}

// F2+F3: col fft over y (ortho), amp/phase, masked channel-mix + gelu
__global__ void k_fft_col(const float* Rre, const float* Rim,
                          float* glo, float* ghi, float* pho,
                          const void* alpw, const void* ahpw,
                          const void* phpw, const void* phs, const int* flg){
  __shared__ float sre[2080], sim[2080];
  __shared__ float og[2080], oh[2080], op[2080];
  __shared__ float Ar[512], Ai[512];
  __shared__ float ct[128], st[128];
  __shared__ float wl[256], wh[256], wp[256];
  int t=threadIdx.x;
  int bf=*flg;
  int b = blockIdx.x/65, v = blockIdx.x%65;
  MAKE_TWP(ct,st);
  wl[t]=LD(alpw,t,bf); wh[t]=LD(ahpw,t,bf); wp[t]=LD(phpw,t,bf);
  long ibase = ((long)b*128)*1040 + v*16;
  for(int e=t;e<2048;e+=256){
    int y=e>>4, c=e&15;
    sre[c*130+y]=Rre[ibase + (long)y*1040 + c];
    sim[c*130+y]=Rim[ibase + (long)y*1040 + c];
  }
  __syncthreads();
  int w=t>>6, l=t&63, wb=w<<7;
  const float inv=1.f/128.f;
  for(int c=w; c<16; c+=4){
    int sb=c*130;
    float x0r=sre[sb+l], x0i=sim[sb+l], x1r=sre[sb+64+l], x1i=sim[sb+64+l];
    int r0=rev7(l), r1=rev7(64+l);
    Ar[wb+r0]=x0r; Ai[wb+r0]=x0i;
    Ar[wb+r1]=x1r; Ai[wb+r1]=x1i;
    fft128(Ar+wb, Ai+wb, ct, st, l, -1.f);
    float re0=Ar[wb+l]*inv, im0=Ai[wb+l]*inv;
    float re1=Ar[wb+64+l]*inv, im1=Ai[wb+64+l]*inv;
    sre[sb+l]=sqrtf(re0*re0+im0*im0); sim[sb+l]=atan2f(im0,re0);
    sre[sb+64+l]=sqrtf(re1*re1+im1*im1); sim[sb+64+l]=atan2f(im1,re1);
  }
  __syncthreads();
  {
    int u = t&127, half = t>>7;
    float yy=(float)u/127.f, xx=(float)v/64.f;
    float rr=sqrtf(yy*yy+xx*xx);
    float lo = 1.f/(1.f+expf((rr-0.25f)*20.f));
    float hi = 1.f-lo;
    float av[16], pv[16];
    for(int ch=0;ch<16;ch++){ av[ch]=sre[ch*130+u]; pv[ch]=sim[ch*130+u]; }
    float pscale = LD(phs,0,bf);
    for(int c=half*8;c<half*8+8;c++){
      float al=0.f, ah=0.f, pp=0.f;
      for(int ch=0;ch<16;ch++){
        float a=av[ch];
        al += wl[c*16+ch]*(a*lo);
        ah += wh[c*16+ch]*(a*hi);
        pp += wp[c*16+ch]*pv[ch];
      }
      og[c*130+u]=geluf(al); oh[c*130+u]=geluf(ah); op[c*130+u]=pv[c]+pscale*pp;
    }
  }
  __syncthreads();
  for(int e=t;e<2048;e+=256){
    int u=e>>4, c=e&15;
    long o = ibase + (long)u*1040 + c;
    glo[o]=og[c*130+u]; ghi[o]=oh[c*130+u]; pho[o]=op[c*130+u];
  }
}

// F4+I1 fused: per (b,v): dw3x3 over (u,v) + Y=amp*e^{i ph} computed in-block,
// then inverse col fft over u. Writes Z[b][y][v][c].
__global__ void k_ifour(const float* glo, const float* ghi, const float* pho,
                        float* Zre, float* Zim,
                        const void* aldw, const void* ahdw, const int* flg){
  __shared__ float sre[2080], sim[2080];
  __shared__ float Ar[512], Ai[512];
  __shared__ float ct[128], st[128];
  __shared__ float wl[144], wh[144];
  int t=threadIdx.x;
  int bf=*flg;
  int b = blockIdx.x/65, v = blockIdx.x%65;
  MAKE_TWP(ct,st);
  if(t<144){ wl[t]=LD(aldw,t,bf); wh[t]=LD(ahdw,t,bf); }
  __syncthreads();
  for(int e=t;e<2048;e+=256){
    int u=e>>4, c=e&15;
    float acc=0.f;
    for(int dp=0;dp<3;dp++){
      int uu=u-1+dp; if(uu<0||uu>=128) continue;
      for(int dq=0;dq<3;dq++){
        int vv=v-1+dq; if(vv<0||vv>=65) continue;
        long idx=(((long)(b*128+uu))*65+vv)*16+c;
        acc += wl[c*9+dp*3+dq]*glo[idx] + wh[c*9+dp*3+dq]*ghi[idx];
      }
    }
    float pvv = pho[(((long)(b*128+u))*65+v)*16+c];
    float s_,c_; sincosf(pvv,&s_,&c_);
    sre[c*130+u]=acc*c_; sim[c*130+u]=acc*s_;
  }
  __syncthreads();
  int w=t>>6, l=t&63, wb=w<<7;
  for(int c=w; c<16; c+=4){
    int sb=c*130;
    float x0r=sre[sb+l], x0i=sim[sb+l], x1r=sre[sb+64+l], x1i=sim[sb+64+l];
    int r0=rev7(l), r1=rev7(64+l);
    Ar[wb+r0]=x0r; Ai[wb+r0]=x0i;
    Ar[wb+r1]=x1r; Ai[wb+r1]=x1i;
    fft128(Ar+wb, Ai+wb, ct, st, l, +1.f);
    sre[sb+l]=Ar[wb+l]; sim[sb+l]=Ai[wb+l];
    sre[sb+64+l]=Ar[wb+64+l]; sim[sb+64+l]=Ai[wb+64+l];
  }
  __syncthreads();
  long ibase = ((long)b*128)*1040 + v*16;
  for(int e=t;e<2048;e+=256){
    int y=e>>4, c=e&15;
    Zre[ibase + (long)y*1040 + c]=sre[c*130+y];
    Zim[ibase + (long)y*1040 + c]=sim[c*130+y];
  }
}

// K3 merged: [0,256) ifft_row + Gkq/Gkk partials | [256,6400) wave_dw | [6400,6528) Gqq
__global__ void k_mix2(const float* Zre, const float* Zim, const float* qm, float* G,
                       const float* m96, float* g96, const void* wdw_, const int* flg){
  __shared__ float smem[9664];
  int blk=blockIdx.x, t=threadIdx.x;
  if(blk<256){
    float* szre=smem; float* szim=smem+2112; float* oslab=smem+4224;
    float* Ar=smem+8384; float* Ai=smem+8896; float* ct=smem+9408; float* st=smem+9536;
    int b = blk>>6, y0 = (blk&63)<<1;
    MAKE_TWP(ct,st);
    long ibase = ((long)(b*128+y0))*1040;
    for(int e=t;e<2080;e+=256){
      int yl=e/1040, rem=e%1040, v=rem>>4, c=rem&15;
      szre[yl*1056 + c*66 + v]=Zre[ibase+e];
      szim[yl*1056 + c*66 + v]=Zim[ibase+e];
    }
    __syncthreads();
    int w=t>>6, l=t&63, wb=w<<7;
    const float inv=1.f/128.f;
    for(int li=w; li<32; li+=4){
      int yl=li>>4, c=li&15;
      int sb = yl*1056 + c*66;
      float zr0 = szre[sb+l];
      float zi0 = (l==0)?0.f:szim[sb+l];
      float zr1, zi1;
      if(l==0){ zr1=szre[sb+64]; zi1=0.f; }
      else    { zr1=szre[sb+64-l]; zi1=-szim[sb+64-l]; }
      int r0=rev7(l), r1=rev7(64+l);
      Ar[wb+r0]=zr0; Ai[wb+r0]=zi0;
      Ar[wb+r1]=zr1; Ai[wb+r1]=zi1;
      fft128(Ar+wb, Ai+wb, ct, st, l, +1.f);
      int ob = yl*2080 + c*130;
      oslab[ob+l]=Ar[wb+l]*inv;
      oslab[ob+64+l]=Ar[wb+64+l]*inv;
    }
    __syncthreads();
    // Gram partials for these 2 rows (km lives in oslab, never stored to global)
    int r=t>>4, s=t&15;
    float akq=0.f, akk=0.f;
    for(int pass=0; pass<2; pass++){
      long qb = ((long)(b*128+y0+pass))<<11;
      for(int i=t;i<2048;i+=256) smem[i]=qm[qb+i];   // overlays dead szre
      __syncthreads();
      int ob = pass*2080;
      for(int p=0;p<128;p++){
        float kv = oslab[ob + r*130 + p];
        akq += kv*smem[p*16+s];
        akk += kv*oslab[ob + s*130 + p];
      }
      __syncthreads();
    }
    float* Gb = G + b*768;
    atomicAdd(&Gb[t], akq);
    atomicAdd(&Gb[256+t], akk);
  } else if(blk<6400){
    int bf=*flg;
    float* wdw=smem;
    for(int i=t;i<864;i+=256) wdw[i]=LD(wdw_,i,bf);
    __syncthreads();
    int o = (blk-256)*256+t;   // 1,572,864 exact
    int ch = o%96; int r = o/96; int px = r&4095; int b = r>>12;
    int i = px>>6, j = px&63;
    long mb = (long)b*393216;
    float acc=0.f;
    for(int dp=0;dp<3;dp++){ int ii=i-1+dp; if(ii<0||ii>=64) continue;
      for(int dq=0;dq<3;dq++){ int jj=j-1+dq; if(jj<0||jj>=64) continue;
        acc += wdw[ch*9+dp*3+dq]*m96[mb + (long)(ii*64+jj)*96 + ch]; } }
    g96[o]=geluf(acc);
  } else {
    int id = blk-6400;         // 0..127
    int b = id>>5, chunk = id&31;
    int r=t>>4, s=t&15;
    float aqq=0.f;
    for(int tile=0;tile<2;tile++){
      long pb = ((long)b*HW + chunk*512 + tile*256)*16;
      for(int i=t;i<4096;i+=256) smem[i]=qm[pb+i];
      __syncthreads();
      for(int p=0;p<256;p++) aqq += smem[p*16+r]*smem[p*16+s];
      __syncthreads();
    }
    atomicAdd(&G[b*768+512+t], aqq);
  }
}

// EPI: per-block attn (Mb from Gram) + mlp_out + residual haar + IWT + @Mb + bproj -> out
__global__ void k_epi(const float* g96, const float* vd, const float* Gg,
                      const void* We, const void* Wproj, const void* resc,
                      const void* wout_, const void* rs_, const void* bproj,
                      void* out, const int* flg){
  int bf=*flg;
  __shared__ float smem[15936];
  int t=threadIdx.x;
  int b=blockIdx.x>>6; int tile=blockIdx.x&63;
  int i0=(tile>>3)<<3, j0=(tile&7)<<3;
  // ---- attention: build mb[16][64] for batch b ----
  float* wes=smem;
  float* gkq=smem+1024; float* gkk=smem+1280; float* gqq=smem+1536;
  float* ukq=smem+1792; float* ukk=smem+2816; float* uqq=smem+3840;
  float* nk=smem+4864;  float* nq=smem+4928;
  float* A=smem+4992;   // 4096
  float* T=smem+9088;   // 1024
  float* mb=smem+14848; // 1024 (persists through epi)
  float* bias=smem+15872;
  if(t<64) bias[t]=LD(bproj,t,bf);
  for(int i=t;i<1024;i+=256) mb[i]=0.f;
  gkq[t]=Gg[b*768+t]; gkk[t]=Gg[b*768+256+t]; gqq[t]=Gg[b*768+512+t];
  __syncthreads();
  for(int h=0;h<8;h++){
    for(int i=t;i<1024;i+=256){ int rr=i>>6, e=i&63; wes[rr*64+e]=LD(We,(long)rr*512+h*64+e,bf); }
    __syncthreads();
    for(int i=t;i<1024;i+=256){
      int d=i>>4, s=i&15;
      float a1=0.f,a2=0.f,a3=0.f;
      for(int rr=0;rr<16;rr++){ float wv=wes[rr*64+d]; a1+=wv*gkq[rr*16+s]; a2+=wv*gkk[rr*16+s]; a3+=wv*gqq[rr*16+s]; }
      ukq[i]=a1; ukk[i]=a2; uqq[i]=a3;
    }
    __syncthreads();
    if(t<64){ float a=0.f; for(int s=0;s<16;s++) a+=ukk[t*16+s]*wes[s*64+t]; nk[t]=fmaxf(sqrtf(a),1e-12f); }
    else if(t<128){ int e=t-64; float a=0.f; for(int s=0;s<16;s++) a+=uqq[e*16+s]*wes[s*64+e]; nq[e]=fmaxf(sqrtf(a),1e-12f); }
    __syncthreads();
    float rsc=LD(resc,h,bf);
    for(int i=t;i<4096;i+=256){
      int d=i>>6, e=i&63;
      float a=0.f; for(int s=0;s<16;s++) a+=ukq[d*16+s]*wes[s*64+e];
      A[i]=a/(nk[d]*nq[e])*rsc;
    }
    __syncthreads();
    if(t<64){
      int d=t; float m=-1e30f;
      for(int e=0;e<64;e++) m=fmaxf(m,A[d*64+e]);
      float sum=0.f;
      for(int e=0;e<64;e++){ float ev=expf(A[d*64+e]-m); A[d*64+e]=ev; sum+=ev; }
      float inv=1.f/sum;
      for(int e=0;e<64;e++) A[d*64+e]*=inv;
    }
    __syncthreads();
    for(int i=t;i<1024;i+=256){
      int d=i>>4, s=i&15;
      float a=0.f; for(int e=0;e<64;e++) a+=A[d*64+e]*wes[s*64+e];
      T[i]=a;
    }
    __syncthreads();
    for(int i=t;i<4096;i+=256){ int d=i>>6, c=i&63; A[i]=LD(Wproj,(long)(h*64+d)*64+c,bf); }
    __syncthreads();
    for(int i=t;i<1024;i+=256){
      int s=i>>6, c=i&63;
      float a=0.f; for(int d=0;d<64;d++) a+=T[d*16+s]*A[d*64+c];
      mb[i]+=a;
    }
    __syncthreads();
  }
  // ---- epilogue ----
  float* wt=smem;          // 0..4608 (attn scratch dead)
  float* gt=smem+4608;     // ..10752
  float* he=smem+10752;    // ..14848
  for(int i=t;i<4608;i+=256){ int ch=i/48, cc=i%48; wt[ch*48+cc]=LD(wout_,(long)cc*96+ch,bf); }
  for(int i=t;i<6144;i+=256){
    int px=i/96, ch=i%96;
    int gi=i0+(px>>3), gj=j0+(px&7);
    gt[i]=g96[((long)b*4096 + gi*64+gj)*96 + ch];
  }
  __syncthreads();
  float rs=LD(rs_,0,bf);
  for(int o=t;o<3072;o+=256){
    int px=o/48, cc=o%48;
    int gi=i0+(px>>3), gj=j0+(px&7);
    float acc=0.f;
    for(int ch=0;ch<96;ch++) acc += wt[ch*48+cc]*gt[px*96+ch];
    long vb = ((long)(b*128+2*gi)*128 + 2*gj)*16;
    int m=cc+16, c=m>>2, f=m&3;
    float a=vd[vb+c], bv=vd[vb+16+c], cv=vd[vb+2048+c], dv=vd[vb+2048+16+c];
    float hv;
    if(f==0)      hv=(a+bv+cv+dv);
    else if(f==1) hv=(a-bv+cv-dv);
    else if(f==2) hv=(a+bv-cv-dv);
    else          hv=(a-bv-cv+dv);
    he[px*64 + 16 + cc] = hv*0.5f + rs*acc;
  }
  for(int o=t;o<1024;o+=256){
    int px=o>>4, c16=o&15;
    int gi=i0+(px>>3), gj=j0+(px&7);
    long vb=((long)(b*128+2*gi)*128+2*gj)*16;
    int c=c16>>2, f=c16&3;
    float a=vd[vb+c], bv=vd[vb+16+c], cv=vd[vb+2048+c], dv=vd[vb+2048+16+c];
    float hv;
    if(f==0)      hv=(a+bv+cv+dv);
    else if(f==1) hv=(a-bv+cv-dv);
    else if(f==2) hv=(a+bv-cv-dv);
    else          hv=(a-bv-cv+dv);
    he[px*64+c16]=hv*0.5f;
  }
  __syncthreads();
  for(int ok=t; ok<16384; ok+=256){
    int c=ok&63, px=ok>>6;
    int orow=px>>4, ocol=px&15;
    int halfpx=(orow>>1)*8 + (ocol>>1);
    int pos=((orow&1)<<1)|(ocol&1);
    const float* hv = he + halfpx*64 + pos*16;
    float acc=bias[c];
    for(int s=0;s<16;s++) acc += hv[s]*mb[s*64+c];
    long oo = (((long)(b*128 + 2*i0+orow))*128 + (2*j0+ocol))*64 + c;
    if(bf) ((__hip_bfloat16*)out)[oo]=__float2bfloat16(acc);
    else   ((float*)out)[oo]=acc;
  }
}

extern "C" void kernel_launch(void* const* d_in, const int* in_sizes, int n_in,
                              void* d_out, int out_size, void* d_ws, size_t ws_size,
                              hipStream_t stream) {
  const void* x_in   = d_in[0];
  const void* Wq     = d_in[1];
  const void* Wk     = d_in[2];
  const void* Wv     = d_in[3];
  const void* Wr     = d_in[4];
  const void* We     = d_in[5];
  const void* qs_dw  = d_in[6];
  const void* qs_pw  = d_in[7];
  const void* qs_g   = d_in[8];
  const void* al_pw  = d_in[9];
  const void* al_dw  = d_in[10];
  const void* ah_pw  = d_in[11];
  const void* ah_dw  = d_in[12];
  const void* ph_pw  = d_in[13];
  const void* ph_s   = d_in[14];
  const void* bn_g   = d_in[15];
  const void* bn_b   = d_in[16];
  const void* mlp_in = d_in[17];
  const void* mlp_dw = d_in[18];
  const void* mlp_out= d_in[19];
  const void* res_s  = d_in[20];
  const void* rescale= d_in[21];
  const void* Wproj  = d_in[22];
  const void* bproj  = d_in[23];
  float* ws = (float*)d_ws;
  const int* flg = ((const int*)ws) + OFF_FLAG;

  float* FA = ws + OFF_S;
  float* FB = FA + FSZ;
  float* FC = FB + FSZ;
  float* FD = FC + FSZ;
  float* FE = FD + FSZ;
  float* M96 = FE + FSZ;            // 1.5M floats
  float* G96 = ws + OFF_QDIM;       // overlays dead qd/kd (dead after k_mix3)

  k_head<<<49,256,0,stream>>>(Wq,Wk,Wv,Wr,bn_g, ws);
  k_dims<<<4096,256,0,stream>>>(x_in, ws, ws+OFF_QDIM, ws+OFF_KDIM, ws+OFF_VDIM, flg);
  // spatial(q) || fft_row(k) || wave_a(v)
  k_mix3<<<1536,256,0,stream>>>(ws+OFF_QDIM, ws+OFF_QMIX, qs_dw, qs_pw, qs_g,
                                ws+OFF_KDIM, FA, FB,
                                ws+OFF_VDIM, M96, mlp_in, bn_g, bn_b, flg);
  k_fft_col<<<260,256,0,stream>>>(FA, FB, FC, FD, FE, al_pw, ah_pw, ph_pw, ph_s, flg);
  // four_dw + ifft_col fused
  k_ifour<<<260,256,0,stream>>>(FC, FD, FE, FA, FB, al_dw, ah_dw, flg);
  // ifft_row+gram_k(k) || wave_dw(v) || gram_q
  k_mix2<<<6528,256,0,stream>>>(FA, FB, ws+OFF_QMIX, ws+OFF_G, M96, G96, mlp_dw, flg);
  // attn + epilogue
  k_epi<<<256,256,0,stream>>>(G96, ws+OFF_VDIM, ws+OFF_G, We, Wproj, rescale,
                              mlp_out, res_s, bproj, d_out, flg);
}

// Round 10
// 398.705 us; speedup vs baseline: 1.7222x; 1.4723x over previous
//
#include <hip/hip_runtime.h>
#include <hip/hip_bf16.h>
#include <math.h>

#define HW 16384

__device__ __forceinline__ float LD(const void* p, long i, int bf){
  return bf ? __bfloat162float(((const __hip_bfloat16*)p)[i]) : ((const float*)p)[i];
}
__device__ __forceinline__ float geluf(float x){ return 0.5f*x*(1.0f + erff(x*0.70710678118654752f)); }
__device__ __forceinline__ int rev7(int i){ return (int)(__brev((unsigned)i)>>25); }

__device__ __forceinline__ void fft128(float* Ar, float* Ai, const float* ct, const float* st,
                                       int lane, float dir){
  #pragma unroll
  for(int len=2; len<=128; len<<=1){
    int half=len>>1;
    int pos = lane & (half-1);
    int i1 = ((lane & ~(half-1))<<1) | pos;
    int i2 = i1 + half;
    int tw = pos * (128/len);
    float wr = ct[tw], wi = dir*st[tw];
    float xr=Ar[i2], xi=Ai[i2];
    float tr = xr*wr - xi*wi;
    float ti = xr*wi + xi*wr;
    float ur=Ar[i1], ui=Ai[i1];
    Ar[i1]=ur+tr; Ai[i1]=ui+ti;
    Ar[i2]=ur-tr; Ai[i2]=ui-ti;
  }
}

#define MAKE_TWP(ct,st) { int tt=threadIdx.x; if(tt<128){ float ang=6.283185307179586f*(float)tt/128.f; float s_,c_; sincosf(ang,&s_,&c_); (ct)[tt]=c_; (st)[tt]=s_; } }

// ---- ws layout (float offsets) ----
#define OFF_M    0
#define OFF_G    3072
#define OFF_MB   6144
#define OFF_FLAG 10240
#define OFF_QDIM 16384
#define OFF_KDIM (16384 + 1048576)
#define OFF_VDIM (16384 + 2*1048576)
#define OFF_QMIX (16384 + 3*1048576)
#define OFF_KMIX (16384 + 4*1048576)
#define OFF_S    (16384 + 5*1048576)
#define FSZ 532480

// K0: fold (48 blocks) + flag/zero (block 48)
__global__ void k_head(const void* Wq, const void* Wk, const void* Wv,
                       const void* Wr, const void* bng, float* ws){
  __shared__ float wr[8192];
  __shared__ float part[256];
  int blk=blockIdx.x, t=threadIdx.x;
  if(blk==48){
    for(int i=3072+t;i<10240;i+=256) ws[i]=0.f;
    if(t==0){
      float v = ((const float*)bng)[0];
      ((int*)ws)[OFF_FLAG] = (v==1.0f) ? 0 : 1;
    }
    return;
  }
  int bf = (((const float*)bng)[0]==1.0f) ? 0 : 1;
  int mat=blk>>4, seg=blk&15;
  const void* Wsrc = mat==0 ? Wq : (mat==1 ? Wk : Wv);
  for(int i=t;i<8192;i+=256) wr[i]=LD(Wr,i,bf);
  __syncthreads();
  int o=t&63, jseg=t>>6;
  int c=seg*4+(o>>4), r=o&15;
  float acc=0.f;
  for(int j=jseg*128;j<jseg*128+128;j++) acc += LD(Wsrc,(long)c*512+j,bf)*wr[j*16+r];
  part[jseg*64+o]=acc;
  __syncthreads();
  if(t<64){
    float s=part[t]+part[64+t]+part[128+t]+part[192+t];
    int cc=seg*4+(t>>4), rr=t&15;
    ws[mat*1024 + cc*16 + rr]=s;
  }
}

// K1: q/k/v_dim = x @ M{q,k,v}
__global__ void k_dims(const void* x, const float* ws,
                       float* qd, float* kd, float* vd, const int* flg){
  int bf=*flg;
  __shared__ float xs[16*64];
  __shared__ float ms[3*1024];
  int b = blockIdx.x>>10;
  int pix0 = (blockIdx.x & 1023)<<4;
  int t = threadIdx.x;
  for(int i=t;i<3072;i+=256) ms[i]=ws[i];
  long base = ((long)b*HW + pix0)*64;
  for(int i=t;i<1024;i+=256) xs[i]=LD(x, base+i, bf);
  __syncthreads();
  int p=t>>4, r=t&15;
  float aq=0.f,ak=0.f,av=0.f;
  for(int c=0;c<64;c++){
    float xv = xs[p*64+c];
    aq += xv*ms[c*16+r];
    ak += xv*ms[1024+c*16+r];
    av += xv*ms[2048+c*16+r];
  }
  long o = ((long)b*HW + pix0)*16 + t;
  qd[o]=aq; kd[o]=ak; vd[o]=av;
}

// K2 merged: [0,256) spatial (2 rows/blk) | [256,512) fft_row | [512,1536) wave_a
__global__ void k_mix3(const float* qd, float* qm, const void* dw, const void* pw, const void* gamma,
                       const float* kd, float* Rre, float* Rim,
                       const float* vd, float* m96, const void* win, const void* bng, const void* bnb,
                       const int* flg){
  __shared__ float smem[9664];
  int bf=*flg;
  int blk=blockIdx.x, t=threadIdx.x;
  if(blk<256){
    float* tile=smem; float* dws=smem+8704; float* pws=smem+8848; float* gsm=smem+9104;
    int b=blk>>6, y0=(blk&63)<<1;
    for(int i=t;i<144;i+=256) dws[i]=LD(dw,i,bf);
    if(t<256) pws[t]=LD(pw,t,bf);
    if(t<16) gsm[t]=LD(gamma,t,bf);
    for(int i=t;i<8192;i+=256){
      int ry=i>>11, rem=i&2047, xx=rem>>4, ch=rem&15;
      int yy=y0-1+ry;
      tile[(ry*128+xx)*17+ch] = (yy>=0&&yy<128) ? qd[(long)(b*128+yy)*2048 + rem] : 0.f;
    }
    __syncthreads();
    int ty=t>>7, x=t&127;
    float g[16];
    for(int ch=0;ch<16;ch++){
      float acc=0.f;
      for(int p=0;p<3;p++)
        for(int q=0;q<3;q++){
          int xx=x-1+q;
          if(xx>=0&&xx<128) acc += dws[ch*9+p*3+q]*tile[((ty+p)*128+xx)*17+ch];
        }
      g[ch]=geluf(acc);
    }
    long ob = ((long)(b*128+y0+ty)*128 + x)*16;
    for(int c=0;c<16;c++){
      float acc=0.f;
      for(int ch=0;ch<16;ch++) acc += pws[c*16+ch]*g[ch];
      qm[ob+c] = tile[((1+ty)*128+x)*17+c] + gsm[c]*acc;
    }
  } else if(blk<512){
    float* slab=smem; float* outre=smem+4160; float* outim=smem+6272;
    float* Ar=smem+8384; float* Ai=smem+8896; float* ct=smem+9408; float* st=smem+9536;
    int blk2=blk-256;
    int b=blk2>>6, y0=(blk2&63)<<1;
    MAKE_TWP(ct,st);
    long gbase = ((long)(b*128+y0))*2048;
    for(int e=t;e<4096;e+=256){
      int yl=e>>11, rem=e&2047, x=rem>>4, c=rem&15;
      slab[yl*2080 + c*130 + x] = kd[gbase + e];
    }
    __syncthreads();
    int w=t>>6, l=t&63, wb=w<<7;
    for(int li=w; li<32; li+=4){
      int yl=li>>4, c=li&15;
      int sb = yl*2080 + c*130;
      float v0=slab[sb+l], v1=slab[sb+64+l];
      int r0=rev7(l), r1=rev7(64+l);
      Ar[wb+r0]=v0; Ai[wb+r0]=0.f;
      Ar[wb+r1]=v1; Ai[wb+r1]=0.f;
      fft128(Ar+wb, Ai+wb, ct, st, l, -1.f);
      int ob = yl*1056 + c*66;
      outre[ob+l]=Ar[wb+l]; outim[ob+l]=Ai[wb+l];
      if(l==0){ outre[ob+64]=Ar[wb+64]; outim[ob+64]=Ai[wb+64]; }
    }
    __syncthreads();
    long obase = ((long)(b*128+y0))*1040;
    for(int e=t;e<2080;e+=256){
      int yl=e/1040, rem=e%1040, v=rem>>4, c=rem&15;
      Rre[obase+e]=outre[yl*1056 + c*66 + v];
      Rim[obase+e]=outim[yl*1056 + c*66 + v];
    }
  } else {
    float* wi=smem; float* vds=smem+4608; float* ns=smem+5632;
    float* gsm=smem+6400; float* bsm=smem+6448;
    int blk3=blk-512;
    int b = blk3>>8;
    int ij0 = (blk3&255)<<4;
    for(int i=t;i<4608;i+=256){ int cc=i/96, ch=i%96; wi[cc*96+ch]=LD(win,(long)ch*48+cc,bf); }
    if(t<48){ gsm[t]=LD(bng,t,bf)*(1.f/sqrtf(1.f+1e-5f)); bsm[t]=LD(bnb,t,bf); }
    int i0 = ij0>>6, j0 = ij0&63;
    long rb0 = ((long)(b*128 + 2*i0)*128 + 2*j0)*16;
    for(int i=t;i<512;i+=256){ vds[i]=vd[rb0+i]; vds[512+i]=vd[rb0+2048+i]; }
    __syncthreads();
    for(int o=t;o<768;o+=256){
      int p=o/48, cc2=o%48;
      int m=cc2+16, c=m>>2, f=m&3;
      float a =vds[(2*p)*16+c],     bv=vds[(2*p+1)*16+c];
      float cv=vds[512+(2*p)*16+c], dv=vds[512+(2*p+1)*16+c];
      float v;
      if(f==0)      v=(a+bv+cv+dv);
      else if(f==1) v=(a-bv+cv-dv);
      else if(f==2) v=(a+bv-cv-dv);
      else          v=(a-bv-cv+dv);
      ns[o] = v*0.5f*gsm[cc2]+bsm[cc2];
    }
    __syncthreads();
    long ob = ((long)b*4096 + ij0)*96;
    for(int o=t;o<1536;o+=256){
      int p=o/96, ch=o%96;
      float acc=0.f;
      for(int cc=0;cc<48;cc++) acc += wi[cc*96+ch]*ns[p*48+cc];
      m96[ob+o]=acc;
    }
  }
}

// F2+F3: col fft over y (ortho), amp/phase, masked channel-mix + gelu
__global__ void k_fft_col(const float* Rre, const float* Rim,
                          float* glo, float* ghi, float* pho,
                          const void* alpw, const void* ahpw,
                          const void* phpw, const void* phs, const int* flg){
  __shared__ float sre[2080], sim[2080];
  __shared__ float og[2080], oh[2080], op[2080];
  __shared__ float Ar[512], Ai[512];
  __shared__ float ct[128], st[128];
  __shared__ float wl[256], wh[256], wp[256];
  int t=threadIdx.x;
  int bf=*flg;
  int b = blockIdx.x/65, v = blockIdx.x%65;
  MAKE_TWP(ct,st);
  wl[t]=LD(alpw,t,bf); wh[t]=LD(ahpw,t,bf); wp[t]=LD(phpw,t,bf);
  long ibase = ((long)b*128)*1040 + v*16;
  for(int e=t;e<2048;e+=256){
    int y=e>>4, c=e&15;
    sre[c*130+y]=Rre[ibase + (long)y*1040 + c];
    sim[c*130+y]=Rim[ibase + (long)y*1040 + c];
  }
  __syncthreads();
  int w=t>>6, l=t&63, wb=w<<7;
  const float inv=1.f/128.f;
  for(int c=w; c<16; c+=4){
    int sb=c*130;
    float x0r=sre[sb+l], x0i=sim[sb+l], x1r=sre[sb+64+l], x1i=sim[sb+64+l];
    int r0=rev7(l), r1=rev7(64+l);
    Ar[wb+r0]=x0r; Ai[wb+r0]=x0i;
    Ar[wb+r1]=x1r; Ai[wb+r1]=x1i;
    fft128(Ar+wb, Ai+wb, ct, st, l, -1.f);
    float re0=Ar[wb+l]*inv, im0=Ai[wb+l]*inv;
    float re1=Ar[wb+64+l]*inv, im1=Ai[wb+64+l]*inv;
    sre[sb+l]=sqrtf(re0*re0+im0*im0); sim[sb+l]=atan2f(im0,re0);
    sre[sb+64+l]=sqrtf(re1*re1+im1*im1); sim[sb+64+l]=atan2f(im1,re1);
  }
  __syncthreads();
  {
    int u = t&127, half = t>>7;
    float yy=(float)u/127.f, xx=(float)v/64.f;
    float rr=sqrtf(yy*yy+xx*xx);
    float lo = 1.f/(1.f+expf((rr-0.25f)*20.f));
    float hi = 1.f-lo;
    float av[16], pv[16];
    for(int ch=0;ch<16;ch++){ av[ch]=sre[ch*130+u]; pv[ch]=sim[ch*130+u]; }
    float pscale = LD(phs,0,bf);
    for(int c=half*8;c<half*8+8;c++){
      float al=0.f, ah=0.f, pp=0.f;
      for(int ch=0;ch<16;ch++){
        float a=av[ch];
        al += wl[c*16+ch]*(a*lo);
        ah += wh[c*16+ch]*(a*hi);
        pp += wp[c*16+ch]*pv[ch];
      }
      og[c*130+u]=geluf(al); oh[c*130+u]=geluf(ah); op[c*130+u]=pv[c]+pscale*pp;
    }
  }
  __syncthreads();
  for(int e=t;e<2048;e+=256){
    int u=e>>4, c=e&15;
    long o = ibase + (long)u*1040 + c;
    glo[o]=og[c*130+u]; ghi[o]=oh[c*130+u]; pho[o]=op[c*130+u];
  }
}

// F4+I1 fused: per (b,v): dw3x3 over (u,v) + Y=amp*e^{i ph}, then inverse col fft.
__global__ void k_ifour(const float* glo, const float* ghi, const float* pho,
                        float* Zre, float* Zim,
                        const void* aldw, const void* ahdw, const int* flg){
  __shared__ float sre[2080], sim[2080];
  __shared__ float Ar[512], Ai[512];
  __shared__ float ct[128], st[128];
  __shared__ float wl[144], wh[144];
  int t=threadIdx.x;
  int bf=*flg;
  int b = blockIdx.x/65, v = blockIdx.x%65;
  MAKE_TWP(ct,st);
  if(t<144){ wl[t]=LD(aldw,t,bf); wh[t]=LD(ahdw,t,bf); }
  __syncthreads();
  for(int e=t;e<2048;e+=256){
    int u=e>>4, c=e&15;
    float acc=0.f;
    for(int dp=0;dp<3;dp++){
      int uu=u-1+dp; if(uu<0||uu>=128) continue;
      for(int dq=0;dq<3;dq++){
        int vv=v-1+dq; if(vv<0||vv>=65) continue;
        long idx=(((long)(b*128+uu))*65+vv)*16+c;
        acc += wl[c*9+dp*3+dq]*glo[idx] + wh[c*9+dp*3+dq]*ghi[idx];
      }
    }
    float pvv = pho[(((long)(b*128+u))*65+v)*16+c];
    float s_,c_; sincosf(pvv,&s_,&c_);
    sre[c*130+u]=acc*c_; sim[c*130+u]=acc*s_;
  }
  __syncthreads();
  int w=t>>6, l=t&63, wb=w<<7;
  for(int c=w; c<16; c+=4){
    int sb=c*130;
    float x0r=sre[sb+l], x0i=sim[sb+l], x1r=sre[sb+64+l], x1i=sim[sb+64+l];
    int r0=rev7(l), r1=rev7(64+l);
    Ar[wb+r0]=x0r; Ai[wb+r0]=x0i;
    Ar[wb+r1]=x1r; Ai[wb+r1]=x1i;
    fft128(Ar+wb, Ai+wb, ct, st, l, +1.f);
    sre[sb+l]=Ar[wb+l]; sim[sb+l]=Ai[wb+l];
    sre[sb+64+l]=Ar[wb+64+l]; sim[sb+64+l]=Ai[wb+64+l];
  }
  __syncthreads();
  long ibase = ((long)b*128)*1040 + v*16;
  for(int e=t;e<2048;e+=256){
    int y=e>>4, c=e&15;
    Zre[ibase + (long)y*1040 + c]=sre[c*130+y];
    Zim[ibase + (long)y*1040 + c]=sim[c*130+y];
  }
}

// K3 merged: [0,256) ifft_row + Gkq/Gkk partials | [256,6400) wave_dw | [6400,6528) Gqq
__global__ void k_mix2(const float* Zre, const float* Zim, const float* qm, float* G,
                       const float* m96, float* g96, const void* wdw_, const int* flg){
  __shared__ float smem[9664];
  int blk=blockIdx.x, t=threadIdx.x;
  if(blk<256){
    float* szre=smem; float* szim=smem+2112; float* oslab=smem+4224;
    float* Ar=smem+8384; float* Ai=smem+8896; float* ct=smem+9408; float* st=smem+9536;
    int b = blk>>6, y0 = (blk&63)<<1;
    MAKE_TWP(ct,st);
    long ibase = ((long)(b*128+y0))*1040;
    for(int e=t;e<2080;e+=256){
      int yl=e/1040, rem=e%1040, v=rem>>4, c=rem&15;
      szre[yl*1056 + c*66 + v]=Zre[ibase+e];
      szim[yl*1056 + c*66 + v]=Zim[ibase+e];
    }
    __syncthreads();
    int w=t>>6, l=t&63, wb=w<<7;
    const float inv=1.f/128.f;
    for(int li=w; li<32; li+=4){
      int yl=li>>4, c=li&15;
      int sb = yl*1056 + c*66;
      float zr0 = szre[sb+l];
      float zi0 = (l==0)?0.f:szim[sb+l];
      float zr1, zi1;
      if(l==0){ zr1=szre[sb+64]; zi1=0.f; }
      else    { zr1=szre[sb+64-l]; zi1=-szim[sb+64-l]; }
      int r0=rev7(l), r1=rev7(64+l);
      Ar[wb+r0]=zr0; Ai[wb+r0]=zi0;
      Ar[wb+r1]=zr1; Ai[wb+r1]=zi1;
      fft128(Ar+wb, Ai+wb, ct, st, l, +1.f);
      int ob = yl*2080 + c*130;
      oslab[ob+l]=Ar[wb+l]*inv;
      oslab[ob+64+l]=Ar[wb+64+l]*inv;
    }
    __syncthreads();
    // Gram partials for these 2 rows (km never goes to global)
    int r=t>>4, s=t&15;
    float akq=0.f, akk=0.f;
    for(int pass=0; pass<2; pass++){
      long qb = ((long)(b*128+y0+pass))<<11;
      for(int i=t;i<2048;i+=256) smem[i]=qm[qb+i];   // overlays dead szre
      __syncthreads();
      int ob = pass*2080;
      for(int p=0;p<128;p++){
        float kv = oslab[ob + r*130 + p];
        akq += kv*smem[p*16+s];
        akk += kv*oslab[ob + s*130 + p];
      }
      __syncthreads();
    }
    float* Gb = G + b*768;
    atomicAdd(&Gb[t], akq);
    atomicAdd(&Gb[256+t], akk);
  } else if(blk<6400){
    int bf=*flg;
    float* wdw=smem;
    for(int i=t;i<864;i+=256) wdw[i]=LD(wdw_,i,bf);
    __syncthreads();
    int o = (blk-256)*256+t;   // 1,572,864 exact
    int ch = o%96; int r = o/96; int px = r&4095; int b = r>>12;
    int i = px>>6, j = px&63;
    long mb = (long)b*393216;
    float acc=0.f;
    for(int dp=0;dp<3;dp++){ int ii=i-1+dp; if(ii<0||ii>=64) continue;
      for(int dq=0;dq<3;dq++){ int jj=j-1+dq; if(jj<0||jj>=64) continue;
        acc += wdw[ch*9+dp*3+dq]*m96[mb + (long)(ii*64+jj)*96 + ch]; } }
    g96[o]=geluf(acc);
  } else {
    int id = blk-6400;         // 0..127
    int b = id>>5, chunk = id&31;
    int r=t>>4, s=t&15;
    float aqq=0.f;
    for(int tile=0;tile<2;tile++){
      long pb = ((long)b*HW + chunk*512 + tile*256)*16;
      for(int i=t;i<4096;i+=256) smem[i]=qm[pb+i];
      __syncthreads();
      for(int p=0;p<256;p++) aqq += smem[p*16+r]*smem[p*16+s];
      __syncthreads();
    }
    atomicAdd(&G[b*768+512+t], aqq);
  }
}

// A2: per (b,h): attn from Gram -> fold into M_b[16,64]  (A padded to stride 65)
__global__ void k_attn(const float* G, float* Mb, const void* We,
                       const void* Wproj, const void* resc, const int* flg){
  int bf=*flg;
  __shared__ float wes[16*64];
  __shared__ float gkq[256], gkk[256], gqq[256];
  __shared__ float ukq[64*16], ukk[64*16], uqq[64*16];
  __shared__ float nk[64], nq[64];
  __shared__ float A[64*65];
  __shared__ float T[64*16];
  __shared__ float wpj[64*64];
  int b=blockIdx.x>>3, h=blockIdx.x&7;
  int t=threadIdx.x;
  for(int i=t;i<1024;i+=256){ int rr=i>>6, e=i&63; wes[rr*64+e]=LD(We, (long)rr*512 + h*64 + e, bf); }
  gkq[t]=G[b*768+t]; gkk[t]=G[b*768+256+t]; gqq[t]=G[b*768+512+t];
  for(int i=t;i<4096;i+=256){ int d=i>>6, c=i&63; wpj[i]=LD(Wproj,(long)(h*64+d)*64+c,bf); }
  __syncthreads();
  for(int i=t;i<1024;i+=256){
    int d=i>>4, s=i&15;
    float a1=0.f,a2=0.f,a3=0.f;
    for(int rr=0;rr<16;rr++){ float wv=wes[rr*64+d]; a1+=wv*gkq[rr*16+s]; a2+=wv*gkk[rr*16+s]; a3+=wv*gqq[rr*16+s]; }
    ukq[i]=a1; ukk[i]=a2; uqq[i]=a3;
  }
  __syncthreads();
  if(t<64){ float a=0.f; for(int s=0;s<16;s++) a+=ukk[t*16+s]*wes[s*64+t]; nk[t]=fmaxf(sqrtf(a),1e-12f); }
  else if(t<128){ int e=t-64; float a=0.f; for(int s=0;s<16;s++) a+=uqq[e*16+s]*wes[s*64+e]; nq[e]=fmaxf(sqrtf(a),1e-12f); }
  __syncthreads();
  float rsc=LD(resc,h,bf);
  for(int i=t;i<4096;i+=256){
    int d=i>>6, e=i&63;
    float a=0.f; for(int s=0;s<16;s++) a+=ukq[d*16+s]*wes[s*64+e];
    A[d*65+e]=a/(nk[d]*nq[e])*rsc;
  }
  __syncthreads();
  if(t<64){
    int d=t; float m=-1e30f;
    for(int e=0;e<64;e++) m=fmaxf(m,A[d*65+e]);
    float sum=0.f;
    for(int e=0;e<64;e++){ float ev=expf(A[d*65+e]-m); A[d*65+e]=ev; sum+=ev; }
    float inv=1.f/sum;
    for(int e=0;e<64;e++) A[d*65+e]*=inv;
  }
  __syncthreads();
  for(int i=t;i<1024;i+=256){
    int d=i>>4, s=i&15;
    float a=0.f; for(int e=0;e<64;e++) a+=A[d*65+e]*wes[s*64+e];
    T[i]=a;
  }
  __syncthreads();
  for(int i=t;i<1024;i+=256){
    int s=i>>6, c=i&63;
    float a=0.f; for(int d=0;d<64;d++) a+=T[d*16+s]*wpj[d*64+c];
    atomicAdd(&Mb[b*1024 + s*64 + c], a);
  }
}

// EPI: mlp_out(96->48) + residual haar + IWT + @M_b + bproj -> d_out
__global__ void k_epi(const float* g96, const float* vd, const float* Mb_,
                      const void* wout_, const void* rs_, const void* bproj,
                      void* out, const int* flg){
  int bf=*flg;
  __shared__ float wt[4608];
  __shared__ float gt[6144];
  __shared__ float he[4096];
  __shared__ float mb[1024];
  __shared__ float bias[64];
  int t=threadIdx.x;
  int b=blockIdx.x>>6; int tile=blockIdx.x&63;
  int i0=(tile>>3)<<3, j0=(tile&7)<<3;
  for(int i=t;i<4608;i+=256){ int ch=i/48, cc=i%48; wt[ch*48+cc]=LD(wout_,(long)cc*96+ch,bf); }
  for(int i=t;i<6144;i+=256){
    int px=i/96, ch=i%96;
    int gi=i0+(px>>3), gj=j0+(px&7);
    gt[i]=g96[((long)b*4096 + gi*64+gj)*96 + ch];
  }
  for(int i=t;i<1024;i+=256) mb[i]=Mb_[b*1024+i];
  if(t<64) bias[t]=LD(bproj,t,bf);
  __syncthreads();
  float rs=LD(rs_,0,bf);
  for(int o=t;o<3072;o+=256){
    int px=o/48, cc=o%48;
    int gi=i0+(px>>3), gj=j0+(px&7);
    float acc=0.f;
    for(int ch=0;ch<96;ch++) acc += wt[ch*48+cc]*gt[px*96+ch];
    long vb = ((long)(b*128+2*gi)*128 + 2*gj)*16;
    int m=cc+16, c=m>>2, f=m&3;
    float a=vd[vb+c], bv=vd[vb+16+c], cv=vd[vb+2048+c], dv=vd[vb+2048+16+c];
    float hv;
    if(f==0)      hv=(a+bv+cv+dv);
    else if(f==1) hv=(a-bv+cv-dv);
    else if(f==2) hv=(a+bv-cv-dv);
    else          hv=(a-bv-cv+dv);
    he[px*64 + 16 + cc] = hv*0.5f + rs*acc;
  }
  for(int o=t;o<1024;o+=256){
    int px=o>>4, c16=o&15;
    int gi=i0+(px>>3), gj=j0+(px&7);
    long vb=((long)(b*128+2*gi)*128+2*gj)*16;
    int c=c16>>2, f=c16&3;
    float a=vd[vb+c], bv=vd[vb+16+c], cv=vd[vb+2048+c], dv=vd[vb+2048+16+c];
    float hv;
    if(f==0)      hv=(a+bv+cv+dv);
    else if(f==1) hv=(a-bv+cv-dv);
    else if(f==2) hv=(a+bv-cv-dv);
    else          hv=(a-bv-cv+dv);
    he[px*64+c16]=hv*0.5f;
  }
  __syncthreads();
  for(int ok=t; ok<16384; ok+=256){
    int c=ok&63, px=ok>>6;
    int orow=px>>4, ocol=px&15;
    int halfpx=(orow>>1)*8 + (ocol>>1);
    int pos=((orow&1)<<1)|(ocol&1);
    const float* hv = he + halfpx*64 + pos*16;
    float acc=bias[c];
    for(int s=0;s<16;s++) acc += hv[s]*mb[s*64+c];
    long oo = (((long)(b*128 + 2*i0+orow))*128 + (2*j0+ocol))*64 + c;
    if(bf) ((__hip_bfloat16*)out)[oo]=__float2bfloat16(acc);
    else   ((float*)out)[oo]=acc;
  }
}

extern "C" void kernel_launch(void* const* d_in, const int* in_sizes, int n_in,
                              void* d_out, int out_size, void* d_ws, size_t ws_size,
                              hipStream_t stream) {
  const void* x_in   = d_in[0];
  const void* Wq     = d_in[1];
  const void* Wk     = d_in[2];
  const void* Wv     = d_in[3];
  const void* Wr     = d_in[4];
  const void* We     = d_in[5];
  const void* qs_dw  = d_in[6];
  const void* qs_pw  = d_in[7];
  const void* qs_g   = d_in[8];
  const void* al_pw  = d_in[9];
  const void* al_dw  = d_in[10];
  const void* ah_pw  = d_in[11];
  const void* ah_dw  = d_in[12];
  const void* ph_pw  = d_in[13];
  const void* ph_s   = d_in[14];
  const void* bn_g   = d_in[15];
  const void* bn_b   = d_in[16];
  const void* mlp_in = d_in[17];
  const void* mlp_dw = d_in[18];
  const void* mlp_out= d_in[19];
  const void* res_s  = d_in[20];
  const void* rescale= d_in[21];
  const void* Wproj  = d_in[22];
  const void* bproj  = d_in[23];
  float* ws = (float*)d_ws;
  const int* flg = ((const int*)ws) + OFF_FLAG;

  float* FA = ws + OFF_S;
  float* FB = FA + FSZ;
  float* FC = FB + FSZ;
  float* FD = FC + FSZ;
  float* FE = FD + FSZ;
  float* M96 = FE + FSZ;            // 1.5M floats
  float* G96 = ws + OFF_QDIM;       // overlays dead qd/kd (dead after k_mix3)

  k_head<<<49,256,0,stream>>>(Wq,Wk,Wv,Wr,bn_g, ws);
  k_dims<<<4096,256,0,stream>>>(x_in, ws, ws+OFF_QDIM, ws+OFF_KDIM, ws+OFF_VDIM, flg);
  // spatial(q) || fft_row(k) || wave_a(v)
  k_mix3<<<1536,256,0,stream>>>(ws+OFF_QDIM, ws+OFF_QMIX, qs_dw, qs_pw, qs_g,
                                ws+OFF_KDIM, FA, FB,
                                ws+OFF_VDIM, M96, mlp_in, bn_g, bn_b, flg);
  k_fft_col<<<260,256,0,stream>>>(FA, FB, FC, FD, FE, al_pw, ah_pw, ph_pw, ph_s, flg);
  // four_dw + ifft_col fused
  k_ifour<<<260,256,0,stream>>>(FC, FD, FE, FA, FB, al_dw, ah_dw, flg);
  // ifft_row+gram_k(k) || wave_dw(v) || gram_q
  k_mix2<<<6528,256,0,stream>>>(FA, FB, ws+OFF_QMIX, ws+OFF_G, M96, G96, mlp_dw, flg);
  k_attn<<<32,256,0,stream>>>(ws+OFF_G, ws+OFF_MB, We, Wproj, rescale, flg);
  k_epi<<<256,256,0,stream>>>(G96, ws+OFF_VDIM, ws+OFF_MB, mlp_out, res_s, bproj, d_out, flg);
}